// Round 3
// baseline (306.789 us; speedup 1.0000x reference)
//
#include <hip/hip_runtime.h>
#include <math.h>

// B=256, D=256, H=8, HD=32, FF=1024, M=2048
#define SCALE_F 0.17677669529663687f

// ---------------- generic NT GEMM: C[M,N] = alpha * A[M,K] @ B[N,K]^T (+bias, relu) ----
// batched over grid.z (zb) with strides, plus optional k-split (partials written at sCk)
__global__ __launch_bounds__(256) void gemm_nt(
    const float* __restrict__ A, int lda, long long sAz,
    const float* __restrict__ Bm, int ldb, long long sBz,
    float* __restrict__ C, int ldc, long long sCz, long long sCk,
    const float* __restrict__ bias,
    int M, int N, int K, float alpha, int relu, int kSplit)
{
    __shared__ float As[16][68];
    __shared__ float Bs[16][68];
    int z = blockIdx.z;
    int zb = z / kSplit, ks = z - zb * kSplit;
    A  += (long long)zb * sAz;
    Bm += (long long)zb * sBz;
    C  += (long long)zb * sCz + (long long)ks * sCk;
    int Klen = K / kSplit;
    int kbeg = ks * Klen, kend = kbeg + Klen;
    int tid = threadIdx.x;
    int tx = tid & 15, ty = tid >> 4;
    int r0 = blockIdx.y * 64, c0 = blockIdx.x * 64;
    float acc[4][4] = {};
    int lrow = tid >> 2, lc4 = (tid & 3) << 2;
    for (int k0 = kbeg; k0 < kend; k0 += 16) {
        float4 va = make_float4(0.f, 0.f, 0.f, 0.f);
        if (r0 + lrow < M) va = *(const float4*)(A + (long long)(r0 + lrow) * lda + k0 + lc4);
        As[lc4 + 0][lrow] = va.x; As[lc4 + 1][lrow] = va.y;
        As[lc4 + 2][lrow] = va.z; As[lc4 + 3][lrow] = va.w;
        float4 vb = make_float4(0.f, 0.f, 0.f, 0.f);
        if (c0 + lrow < N) vb = *(const float4*)(Bm + (long long)(c0 + lrow) * ldb + k0 + lc4);
        Bs[lc4 + 0][lrow] = vb.x; Bs[lc4 + 1][lrow] = vb.y;
        Bs[lc4 + 2][lrow] = vb.z; Bs[lc4 + 3][lrow] = vb.w;
        __syncthreads();
        #pragma unroll
        for (int k = 0; k < 16; ++k) {
            float4 a4 = *(const float4*)&As[k][ty << 2];
            float4 b4 = *(const float4*)&Bs[k][tx << 2];
            float a[4] = {a4.x, a4.y, a4.z, a4.w};
            float b[4] = {b4.x, b4.y, b4.z, b4.w};
            #pragma unroll
            for (int i = 0; i < 4; i++)
                #pragma unroll
                for (int j = 0; j < 4; j++)
                    acc[i][j] = fmaf(a[i], b[j], acc[i][j]);
        }
        __syncthreads();
    }
    #pragma unroll
    for (int i = 0; i < 4; i++) {
        int r = r0 + (ty << 2) + i;
        if (r >= M) continue;
        #pragma unroll
        for (int j = 0; j < 4; j++) {
            int c = c0 + (tx << 2) + j;
            if (c >= N) continue;
            float v = acc[i][j] * alpha;
            if (bias) v += bias[c];
            if (relu) v = fmaxf(v, 0.f);
            C[(long long)r * ldc + c] = v;
        }
    }
}

__global__ void reduce_parts(const float* __restrict__ parts, int np, long long stride,
                             const float* __restrict__ bias, int N, int relu,
                             float* __restrict__ out, int total)
{
    int i = blockIdx.x * 256 + threadIdx.x;
    if (i >= total) return;
    float s = 0.f;
    for (int p = 0; p < np; p++) s += parts[(long long)p * stride + i];
    if (bias) s += bias[i % N];
    if (relu) s = fmaxf(s, 0.f);
    out[i] = s;
}

// fused k-split reduce + bias + residual + LayerNorm (rows of 256)
__global__ __launch_bounds__(256) void ln_red_k(const float* __restrict__ parts, int np,
        const float* __restrict__ bias, const float* __restrict__ resid,
        const float* __restrict__ g, const float* __restrict__ be, float* __restrict__ O)
{
    int r = blockIdx.x, t = threadIdx.x;
    __shared__ float red[256];
    float x = bias[t] + resid[r * 256 + t];
    for (int p = 0; p < np; p++) x += parts[(long long)p * 65536 + r * 256 + t];
    red[t] = x; __syncthreads();
    for (int s = 128; s; s >>= 1) { if (t < s) red[t] += red[t + s]; __syncthreads(); }
    float mean = red[0] * (1.f / 256.f); __syncthreads();
    float c = x - mean;
    red[t] = c * c; __syncthreads();
    for (int s = 128; s; s >>= 1) { if (t < s) red[t] += red[t + s]; __syncthreads(); }
    float rstd = rsqrtf(red[0] * (1.f / 256.f) + 1e-5f);
    O[r * 256 + t] = c * rstd * g[t] + be[t];
}

// per-row L2 norms: rows 0..255 = src, rows 256..2303 = memory
__global__ void row_norms(const float* __restrict__ src, const float* __restrict__ mem,
                          float* __restrict__ nx, float* __restrict__ nm, float* __restrict__ nm2)
{
    int r = blockIdx.x;
    int lane = threadIdx.x;          // 64 lanes
    const float* row = (r < 256) ? (src + (long long)r * 256) : (mem + (long long)(r - 256) * 256);
    float4 v = *(const float4*)(row + lane * 4);
    float ss = v.x * v.x + v.y * v.y + v.z * v.z + v.w * v.w;
    for (int off = 32; off; off >>= 1) ss += __shfl_down(ss, off, 64);
    if (lane == 0) {
        if (r < 256) nx[r] = fmaxf(sqrtf(ss), 1e-8f);
        else { nm[r - 256] = fmaxf(sqrtf(ss), 1e-8f); nm2[r - 256] = ss; }
    }
}

// surprises[b] = total==0 ? 1 : 1 - max_m (sum_p simdot_p)/(nx[b]*nm[m])
__global__ __launch_bounds__(256) void surprise_k(const float* __restrict__ simdot, int np,
        long long pstride,
        const float* __restrict__ nx, const float* __restrict__ nm, const float* __restrict__ nm2,
        float* __restrict__ sur)
{
    __shared__ float red[256];
    int b = blockIdx.x, t = threadIdx.x;
    float tot = 0.f;
    for (int m = t; m < 2048; m += 256) tot += nm2[m];
    red[t] = tot; __syncthreads();
    for (int s = 128; s; s >>= 1) { if (t < s) red[t] += red[t + s]; __syncthreads(); }
    float total = red[0];
    __syncthreads();
    float invx = 1.f / nx[b];
    float mx = -1e30f;
    for (int m = t; m < 2048; m += 256) {
        float d = 0.f;
        for (int p = 0; p < np; p++) d += simdot[(long long)p * pstride + (long long)b * 2048 + m];
        float s = d * invx / nm[m];
        mx = fmaxf(mx, s);
    }
    red[t] = mx; __syncthreads();
    for (int s = 128; s; s >>= 1) { if (t < s) red[t] = fmaxf(red[t], red[t + s]); __syncthreads(); }
    if (t == 0) sur[b] = (total == 0.f) ? 1.f : 1.f - red[0];
}

// ---------------- fused flash attention ----------------
// grid (32 q-tiles of 8 rows, 8 heads), 512 threads.
// qkv [256][768] (q | k_src | v_src per row), kv [2048][512] (k_mem | v_mem per row).
// K,V read straight from L2 (4 MB total, heavily reused); probs chunk lives in LDS.
#define LSP 68
__global__ __launch_bounds__(512) void attn_k(const float* __restrict__ qkv,
        const float* __restrict__ kv, float* __restrict__ ctx)
{
    int h = blockIdx.y, b0 = blockIdx.x * 8;
    int t = threadIdx.x;
    __shared__ float Qs[8][33];
    __shared__ float Ls[8][LSP];
    __shared__ float s_m[8], s_l[8], s_al[8];

    int qa = t & 7, ml = t >> 3;               // phase A: one logit each
    int qb = t >> 6, db = t & 63;              // phase B: one chunk-logit each
    int qc = t >> 6, dc = (t >> 1) & 31, mh = t & 1;  // phase C: (q,d) pairs split over m

    // Q row (scaled) in registers for phase A
    float4 qr[8];
    {
        const float* qrow = qkv + (b0 + qa) * 768 + h * 32;
        #pragma unroll
        for (int i = 0; i < 8; i++) {
            float4 v = *(const float4*)(qrow + i * 4);
            qr[i] = make_float4(v.x * SCALE_F, v.y * SCALE_F, v.z * SCALE_F, v.w * SCALE_F);
        }
    }
    if (t < 256) {
        int q = t >> 5, d = t & 31;
        Qs[q][d] = qkv[(b0 + q) * 768 + h * 32 + d] * SCALE_F;
    }
    if (t < 8) { s_m[t] = -1e30f; s_l[t] = 0.f; }
    float acc = 0.f;
    __syncthreads();

    const float* Kbase = kv + h * 32;
    const float* Vbase = kv + 256 + h * 32;

    for (int m0 = 0; m0 < 2048; m0 += 64) {
        // phase A: logit(qa, m0+ml)
        {
            const float* krow = Kbase + (long long)(m0 + ml) * 512;
            float s = 0.f;
            #pragma unroll
            for (int i = 0; i < 8; i++) {
                float4 k4 = *(const float4*)(krow + i * 4);
                s = fmaf(qr[i].x, k4.x, s); s = fmaf(qr[i].y, k4.y, s);
                s = fmaf(qr[i].z, k4.z, s); s = fmaf(qr[i].w, k4.w, s);
            }
            Ls[qa][ml] = s;
        }
        __syncthreads();
        // phase B: online softmax update per q over the 64 chunk logits
        {
            float l = Ls[qb][db];
            float cm = l;
            #pragma unroll
            for (int off = 32; off; off >>= 1) cm = fmaxf(cm, __shfl_xor(cm, off, 64));
            float mold = s_m[qb];
            float newm = fmaxf(mold, cm);
            float al = __expf(mold - newm);
            float p = __expf(l - newm);
            float cs = p;
            #pragma unroll
            for (int off = 32; off; off >>= 1) cs += __shfl_xor(cs, off, 64);
            Ls[qb][db] = p;
            if (db == 0) { s_m[qb] = newm; s_l[qb] = s_l[qb] * al + cs; s_al[qb] = al; }
        }
        __syncthreads();
        // phase C: acc(q,d) over this chunk's 64 m (split in halves over lane pairs)
        {
            float a2 = acc * s_al[qc];
            int mb = mh * 32;
            #pragma unroll
            for (int m4 = 0; m4 < 32; m4 += 4) {
                float4 p = *(const float4*)&Ls[qc][mb + m4];
                const float* vcol = Vbase + (long long)(m0 + mb + m4) * 512 + dc;
                float v0 = vcol[0], v1 = vcol[512], v2 = vcol[1024], v3 = vcol[1536];
                a2 = fmaf(p.x, v0, a2); a2 = fmaf(p.y, v1, a2);
                a2 = fmaf(p.z, v2, a2); a2 = fmaf(p.w, v3, a2);
            }
            acc = a2;
        }
        __syncthreads();
    }
    // self-attention logit + final normalize
    {
        float ks = qkv[(b0 + qc) * 768 + 256 + h * 32 + dc];
        float slp = (mh == 0) ? Qs[qc][dc] * ks : 0.f;
        #pragma unroll
        for (int off = 32; off; off >>= 1) slp += __shfl_xor(slp, off, 64);
        float sl = slp;
        float vs = qkv[(b0 + qc) * 768 + 512 + h * 32 + dc];
        float tot = acc + __shfl_xor(acc, 1, 64);
        float mr = s_m[qc], lrun = s_l[qc];
        float Mf = fmaxf(mr, sl);
        float es = __expf(sl - Mf);
        float al = __expf(mr - Mf);
        float lf = lrun * al + es;
        if (mh == 0)
            ctx[(b0 + qc) * 256 + h * 32 + dc] = (tot * al + es * vs) / lf;
    }
}

// sequential accept scan (faithful to lax.scan semantics); inv[m] = source row b or -1
__global__ __launch_bounds__(256) void accept_k(const float* __restrict__ sur,
        const int* __restrict__ ptr, int* __restrict__ inv)
{
    int t = threadIdx.x;
    __shared__ float s_s[256];
    s_s[t] = sur[t];
    for (int m = t; m < 2048; m += 256) inv[m] = -1;
    __syncthreads();
    if (t == 0) {
        long long p = ptr[0];
        for (int b = 0; b < 256; ++b) {
            bool cond = (s_s[b] > 0.5f) || (p < 2048);
            if (cond) { inv[(int)(p % 2048)] = b; p++; }
        }
    }
}

__global__ __launch_bounds__(256) void memupd_k(const float* __restrict__ memory,
        const float* __restrict__ momentum, const float* __restrict__ scores,
        const float* __restrict__ hbuf, const float* __restrict__ sur, const int* __restrict__ inv,
        float* __restrict__ mem_o, float* __restrict__ mom_o, float* __restrict__ sc_o)
{
    int m = blockIdx.x, t = threadIdx.x;
    int b = inv[m];
    long long o = (long long)m * 256 + t;
    float xm = memory[o], mo = momentum[o];
    if (b >= 0) {
        float diff = hbuf[b * 256 + t] - xm;
        float nmom = 0.9f * mo + 0.1f * diff;
        mem_o[o] = xm + 0.1f * nmom;
        mom_o[o] = nmom;
        if (t == 0) sc_o[m] = sur[b];
    } else {
        mem_o[o] = xm;
        mom_o[o] = mo;
        if (t == 0) sc_o[m] = scores[m];
    }
}

extern "C" void kernel_launch(void* const* d_in, const int* in_sizes, int n_in,
                              void* d_out, int out_size, void* d_ws, size_t ws_size,
                              hipStream_t stream)
{
    const float* src      = (const float*)d_in[0];
    const float* memory   = (const float*)d_in[1];
    const float* momentum = (const float*)d_in[2];
    const float* scores   = (const float*)d_in[3];
    const float* ipw      = (const float*)d_in[4];
    const float* ipb      = (const float*)d_in[5];
    const float* out_w    = (const float*)d_in[6];
    const float* out_b    = (const float*)d_in[7];
    const float* w1       = (const float*)d_in[8];
    const float* b1       = (const float*)d_in[9];
    const float* w2       = (const float*)d_in[10];
    const float* b2       = (const float*)d_in[11];
    const float* g1       = (const float*)d_in[12];
    const float* be1      = (const float*)d_in[13];
    const float* g2       = (const float*)d_in[14];
    const float* be2      = (const float*)d_in[15];
    const int*   ptr      = (const int*)d_in[16];

    float* o = (float*)d_out;
    float* out_main = o;
    float* mem_o = o + 65536;
    float* mom_o = mem_o + 524288;
    float* sc_o  = mom_o + 524288;

    float* ws = (float*)d_ws;
    float* qkv       = ws;                       // 196608
    float* kv        = qkv + 196608;             // 1048576
    float* simdot_p  = kv + 1048576;             // 2 * 524288
    float* nx        = simdot_p + 1048576;       // 256
    float* nm        = nx + 256;                 // 2048
    float* nm2       = nm + 2048;                // 2048
    float* sur       = nm2 + 2048;               // 256
    float* ctx       = sur + 256;                // 65536
    float* hbuf      = ctx + 65536;              // 65536
    float* ff1       = hbuf + 65536;             // 262144
    int*   inv       = (int*)(ff1 + 262144);     // 2048
    float* qkv_part  = (float*)(inv + 2048);     // 4 * 196608
    float* attn_part = qkv_part + 786432;        // 8 * 65536
    float* ff1_part  = attn_part + 524288;       // 4 * 262144
    float* ff2_part  = ff1_part + 1048576;       // 16 * 65536

    row_norms<<<2304, 64, 0, stream>>>(src, memory, nx, nm, nm2);

    // qkv_src [256,768] = src @ ipw^T + ipb  (k-split 4 -> 192 blocks)
    gemm_nt<<<dim3(12, 4, 4), 256, 0, stream>>>(src, 256, 0, ipw, 256, 0,
        qkv_part, 768, 0, 196608, nullptr, 256, 768, 256, 1.f, 0, 4);
    reduce_parts<<<768, 256, 0, stream>>>(qkv_part, 4, 196608, ipb, 768, 0, qkv, 196608);

    // kv_mem [2048,512] = memory @ ipw[256:768]^T + ipb[256:768]  (256 blocks)
    gemm_nt<<<dim3(8, 32, 1), 256, 0, stream>>>(memory, 256, 0, ipw + 65536, 256, 0,
        kv, 512, 0, 0, ipb + 256, 2048, 512, 256, 1.f, 0, 1);

    // simdot [256,2048] = src @ memory^T  (k-split 2 -> 256 blocks)
    gemm_nt<<<dim3(32, 4, 2), 256, 0, stream>>>(src, 256, 0, memory, 256, 0,
        simdot_p, 2048, 0, 524288, nullptr, 256, 2048, 256, 1.f, 0, 2);
    surprise_k<<<256, 256, 0, stream>>>(simdot_p, 2, 524288, nx, nm, nm2, sur);

    // fused attention -> ctx
    attn_k<<<dim3(32, 8), 512, 0, stream>>>(qkv, kv, ctx);

    // attn_out partials = ctx @ out_w^T  (k-split 8 -> 128 blocks)
    gemm_nt<<<dim3(4, 4, 8), 256, 0, stream>>>(ctx, 256, 0, out_w, 256, 0,
        attn_part, 256, 0, 65536, nullptr, 256, 256, 256, 1.f, 0, 8);
    // h = LN(src + attn_out + out_b)
    ln_red_k<<<256, 256, 0, stream>>>(attn_part, 8, out_b, src, g1, be1, hbuf);

    accept_k<<<1, 256, 0, stream>>>(sur, ptr, inv);
    memupd_k<<<2048, 256, 0, stream>>>(memory, momentum, scores, hbuf, sur, inv, mem_o, mom_o, sc_o);

    // ff1 = relu(h @ w1^T + b1)  (k-split 4 -> 256 blocks)
    gemm_nt<<<dim3(16, 4, 4), 256, 0, stream>>>(hbuf, 256, 0, w1, 256, 0,
        ff1_part, 1024, 0, 262144, nullptr, 256, 1024, 256, 1.f, 0, 4);
    reduce_parts<<<1024, 256, 0, stream>>>(ff1_part, 4, 262144, b1, 1024, 1, ff1, 262144);

    // ff2 partials = ff1 @ w2^T  (k-split 16 -> 256 blocks)
    gemm_nt<<<dim3(4, 4, 16), 256, 0, stream>>>(ff1, 1024, 0, w2, 1024, 0,
        ff2_part, 256, 0, 65536, nullptr, 256, 256, 1024, 1.f, 0, 16);
    // out = LN(h + ff2 + b2)
    ln_red_k<<<256, 256, 0, stream>>>(ff2_part, 16, b2, hbuf, g2, be2, out_main);
}

// Round 4
// 296.598 us; speedup vs baseline: 1.0344x; 1.0344x over previous
//
#include <hip/hip_runtime.h>
#include <math.h>

// B=256, D=256, H=8, HD=32, FF=1024, M=2048
#define SCALE_F 0.17677669529663687f

// ---------------- generic NT GEMM: C[M,N] = alpha * A[M,K] @ B[N,K]^T (+bias, relu) ----
// batched over grid.z (zb) with strides, plus optional k-split (partials written at sCk)
// transC: write C[c*ldc + r] instead of C[r*ldc + c] (used to emit K^T/V^T layout directly)
__global__ __launch_bounds__(256) void gemm_nt(
    const float* __restrict__ A, int lda, long long sAz,
    const float* __restrict__ Bm, int ldb, long long sBz,
    float* __restrict__ C, int ldc, long long sCz, long long sCk,
    const float* __restrict__ bias,
    int M, int N, int K, float alpha, int relu, int kSplit, int transC)
{
    __shared__ float As[16][68];
    __shared__ float Bs[16][68];
    int z = blockIdx.z;
    int zb = z / kSplit, ks = z - zb * kSplit;
    A  += (long long)zb * sAz;
    Bm += (long long)zb * sBz;
    C  += (long long)zb * sCz + (long long)ks * sCk;
    int Klen = K / kSplit;
    int kbeg = ks * Klen, kend = kbeg + Klen;
    int tid = threadIdx.x;
    int tx = tid & 15, ty = tid >> 4;
    int r0 = blockIdx.y * 64, c0 = blockIdx.x * 64;
    float acc[4][4] = {};
    int lrow = tid >> 2, lc4 = (tid & 3) << 2;
    for (int k0 = kbeg; k0 < kend; k0 += 16) {
        float4 va = make_float4(0.f, 0.f, 0.f, 0.f);
        if (r0 + lrow < M) va = *(const float4*)(A + (long long)(r0 + lrow) * lda + k0 + lc4);
        As[lc4 + 0][lrow] = va.x; As[lc4 + 1][lrow] = va.y;
        As[lc4 + 2][lrow] = va.z; As[lc4 + 3][lrow] = va.w;
        float4 vb = make_float4(0.f, 0.f, 0.f, 0.f);
        if (c0 + lrow < N) vb = *(const float4*)(Bm + (long long)(c0 + lrow) * ldb + k0 + lc4);
        Bs[lc4 + 0][lrow] = vb.x; Bs[lc4 + 1][lrow] = vb.y;
        Bs[lc4 + 2][lrow] = vb.z; Bs[lc4 + 3][lrow] = vb.w;
        __syncthreads();
        #pragma unroll
        for (int k = 0; k < 16; ++k) {
            float4 a4 = *(const float4*)&As[k][ty << 2];
            float4 b4 = *(const float4*)&Bs[k][tx << 2];
            float a[4] = {a4.x, a4.y, a4.z, a4.w};
            float b[4] = {b4.x, b4.y, b4.z, b4.w};
            #pragma unroll
            for (int i = 0; i < 4; i++)
                #pragma unroll
                for (int j = 0; j < 4; j++)
                    acc[i][j] = fmaf(a[i], b[j], acc[i][j]);
        }
        __syncthreads();
    }
    #pragma unroll
    for (int i = 0; i < 4; i++) {
        int r = r0 + (ty << 2) + i;
        if (r >= M) continue;
        #pragma unroll
        for (int j = 0; j < 4; j++) {
            int c = c0 + (tx << 2) + j;
            if (c >= N) continue;
            float v = acc[i][j] * alpha;
            if (bias) v += bias[c];
            if (relu) v = fmaxf(v, 0.f);
            if (transC) C[(long long)c * ldc + r] = v;
            else        C[(long long)r * ldc + c] = v;
        }
    }
}

__global__ void reduce_parts(const float* __restrict__ parts, int np, long long stride,
                             const float* __restrict__ bias, int N, int relu,
                             float* __restrict__ out, int total)
{
    int i = blockIdx.x * 256 + threadIdx.x;
    if (i >= total) return;
    float s = 0.f;
    for (int p = 0; p < np; p++) s += parts[(long long)p * stride + i];
    if (bias) s += bias[i % N];
    if (relu) s = fmaxf(s, 0.f);
    out[i] = s;
}

// fused k-split reduce + bias + residual + LayerNorm (rows of 256)
__global__ __launch_bounds__(256) void ln_red_k(const float* __restrict__ parts, int np,
        const float* __restrict__ bias, const float* __restrict__ resid,
        const float* __restrict__ g, const float* __restrict__ be, float* __restrict__ O)
{
    int r = blockIdx.x, t = threadIdx.x;
    __shared__ float red[256];
    float x = bias[t] + resid[r * 256 + t];
    for (int p = 0; p < np; p++) x += parts[(long long)p * 65536 + r * 256 + t];
    red[t] = x; __syncthreads();
    for (int s = 128; s; s >>= 1) { if (t < s) red[t] += red[t + s]; __syncthreads(); }
    float mean = red[0] * (1.f / 256.f); __syncthreads();
    float c = x - mean;
    red[t] = c * c; __syncthreads();
    for (int s = 128; s; s >>= 1) { if (t < s) red[t] += red[t + s]; __syncthreads(); }
    float rstd = rsqrtf(red[0] * (1.f / 256.f) + 1e-5f);
    O[r * 256 + t] = c * rstd * g[t] + be[t];
}

// per-row L2 norms: rows 0..255 = src, rows 256..2303 = memory
__global__ void row_norms(const float* __restrict__ src, const float* __restrict__ mem,
                          float* __restrict__ nx, float* __restrict__ nm, float* __restrict__ nm2)
{
    int r = blockIdx.x;
    int lane = threadIdx.x;          // 64 lanes
    const float* row = (r < 256) ? (src + (long long)r * 256) : (mem + (long long)(r - 256) * 256);
    float4 v = *(const float4*)(row + lane * 4);
    float ss = v.x * v.x + v.y * v.y + v.z * v.z + v.w * v.w;
    for (int off = 32; off; off >>= 1) ss += __shfl_down(ss, off, 64);
    if (lane == 0) {
        if (r < 256) nx[r] = fmaxf(sqrtf(ss), 1e-8f);
        else { nm[r - 256] = fmaxf(sqrtf(ss), 1e-8f); nm2[r - 256] = ss; }
    }
}

// surprises[b] = total==0 ? 1 : 1 - max_m (sum_p simdot_p)/(nx[b]*nm[m])
__global__ __launch_bounds__(256) void surprise_k(const float* __restrict__ simdot, int np,
        long long pstride,
        const float* __restrict__ nx, const float* __restrict__ nm, const float* __restrict__ nm2,
        float* __restrict__ sur)
{
    __shared__ float red[256];
    int b = blockIdx.x, t = threadIdx.x;
    float tot = 0.f;
    for (int m = t; m < 2048; m += 256) tot += nm2[m];
    red[t] = tot; __syncthreads();
    for (int s = 128; s; s >>= 1) { if (t < s) red[t] += red[t + s]; __syncthreads(); }
    float total = red[0];
    __syncthreads();
    float invx = 1.f / nx[b];
    float mx = -1e30f;
    for (int m = t; m < 2048; m += 256) {
        float d = 0.f;
        for (int p = 0; p < np; p++) d += simdot[(long long)p * pstride + (long long)b * 2048 + m];
        float s = d * invx / nm[m];
        mx = fmaxf(mx, s);
    }
    red[t] = mx; __syncthreads();
    for (int s = 128; s; s >>= 1) { if (t < s) red[t] = fmaxf(red[t], red[t + s]); __syncthreads(); }
    if (t == 0) sur[b] = (total == 0.f) ? 1.f : 1.f - red[0];
}

// ---------------- fused flash attention v2: barrier-free, wave-per-(b,h)-row ----------
// qkv  [256][768] rows (q | k_src | v_src)
// ktvt [512][2048]: rows 0..255 = K^T (row h*32+d = K[.][h][d] over m), rows 256..511 = V^T
// Each wave owns one (b,h): coalesced float4 K^T/V^T loads, online softmax via shfl,
// P transposed through a private LDS row (broadcast reads). No __syncthreads at all.
__global__ __launch_bounds__(256) void attn_k(const float* __restrict__ qkv,
        const float* __restrict__ ktvt, float* __restrict__ ctx)
{
    int h = blockIdx.y;
    int w = threadIdx.x >> 6, lane = threadIdx.x & 63;
    int b = blockIdx.x * 4 + w;
    __shared__ float p_lds[4][256];

    // q row (pre-scaled) in registers
    float4 q4[8];
    const float* qrow = qkv + b * 768 + h * 32;
    #pragma unroll
    for (int i = 0; i < 8; i++) {
        float4 v = *(const float4*)(qrow + i * 4);
        q4[i] = make_float4(v.x * SCALE_F, v.y * SCALE_F, v.z * SCALE_F, v.w * SCALE_F);
    }
    const float* KT = ktvt + (long long)(h * 32) * 2048;
    const float* VT = ktvt + (long long)(256 + h * 32) * 2048;

    int d = lane & 31, half = lane >> 5;
    const float* vbase = VT + (long long)d * 2048 + half * 128;

    float mrun = -1e30f, lrun = 0.f, acc = 0.f;

    for (int m0 = 0; m0 < 2048; m0 += 256) {
        int mI = m0 + lane * 4;
        // ---- logits for 4 m per lane (coalesced float4 K^T loads) ----
        float s0 = 0.f, s1 = 0.f, s2 = 0.f, s3 = 0.f;
        #pragma unroll
        for (int i = 0; i < 8; i++) {
            const float* kb = KT + (long long)(i * 4) * 2048 + mI;
            float4 ka = *(const float4*)(kb);
            float4 kbv = *(const float4*)(kb + 2048);
            float4 kc = *(const float4*)(kb + 4096);
            float4 kd = *(const float4*)(kb + 6144);
            s0 = fmaf(q4[i].x, ka.x, s0);  s1 = fmaf(q4[i].x, ka.y, s1);
            s2 = fmaf(q4[i].x, ka.z, s2);  s3 = fmaf(q4[i].x, ka.w, s3);
            s0 = fmaf(q4[i].y, kbv.x, s0); s1 = fmaf(q4[i].y, kbv.y, s1);
            s2 = fmaf(q4[i].y, kbv.z, s2); s3 = fmaf(q4[i].y, kbv.w, s3);
            s0 = fmaf(q4[i].z, kc.x, s0);  s1 = fmaf(q4[i].z, kc.y, s1);
            s2 = fmaf(q4[i].z, kc.z, s2);  s3 = fmaf(q4[i].z, kc.w, s3);
            s0 = fmaf(q4[i].w, kd.x, s0);  s1 = fmaf(q4[i].w, kd.y, s1);
            s2 = fmaf(q4[i].w, kd.z, s2);  s3 = fmaf(q4[i].w, kd.w, s3);
        }
        // ---- online softmax update ----
        float cm = fmaxf(fmaxf(s0, s1), fmaxf(s2, s3));
        #pragma unroll
        for (int off = 32; off; off >>= 1) cm = fmaxf(cm, __shfl_xor(cm, off, 64));
        float newm = fmaxf(mrun, cm);
        float al = __expf(mrun - newm);
        float p0 = __expf(s0 - newm), p1 = __expf(s1 - newm);
        float p2 = __expf(s2 - newm), p3 = __expf(s3 - newm);
        float cs = p0 + p1 + p2 + p3;
        #pragma unroll
        for (int off = 32; off; off >>= 1) cs += __shfl_xor(cs, off, 64);
        lrun = lrun * al + cs;
        mrun = newm;
        *(float4*)&p_lds[w][lane * 4] = make_float4(p0, p1, p2, p3);
        // ---- PV: lane -> (d, m-half); coalesced V^T float4 loads, P broadcast from LDS ----
        acc *= al;
        const float* vb = vbase + m0;
        #pragma unroll
        for (int i = 0; i < 32; i++) {
            float4 pv = *(const float4*)&p_lds[w][half * 128 + i * 4];
            float4 vv = *(const float4*)(vb + i * 4);
            acc = fmaf(pv.x, vv.x, acc); acc = fmaf(pv.y, vv.y, acc);
            acc = fmaf(pv.z, vv.z, acc); acc = fmaf(pv.w, vv.w, acc);
        }
    }
    // ---- self-attention logit + final normalize ----
    const float* ks = qkv + b * 768 + 256 + h * 32;
    float sl = 0.f;
    #pragma unroll
    for (int i = 0; i < 8; i++) {
        float4 k4 = *(const float4*)(ks + i * 4);
        sl = fmaf(q4[i].x, k4.x, sl); sl = fmaf(q4[i].y, k4.y, sl);
        sl = fmaf(q4[i].z, k4.z, sl); sl = fmaf(q4[i].w, k4.w, sl);
    }
    float Mf = fmaxf(mrun, sl);
    float es = __expf(sl - Mf);
    float alf = __expf(mrun - Mf);
    float lf = lrun * alf + es;
    float tot = acc + __shfl_xor(acc, 32, 64);
    if (lane < 32) {
        float vs = qkv[b * 768 + 512 + h * 32 + d];
        ctx[b * 256 + h * 32 + d] = (tot * alf + es * vs) / lf;
    }
}

// sequential accept scan (faithful to lax.scan semantics); inv[m] = source row b or -1
__global__ __launch_bounds__(256) void accept_k(const float* __restrict__ sur,
        const int* __restrict__ ptr, int* __restrict__ inv)
{
    int t = threadIdx.x;
    __shared__ float s_s[256];
    s_s[t] = sur[t];
    for (int m = t; m < 2048; m += 256) inv[m] = -1;
    __syncthreads();
    if (t == 0) {
        long long p = ptr[0];
        for (int b = 0; b < 256; ++b) {
            bool cond = (s_s[b] > 0.5f) || (p < 2048);
            if (cond) { inv[(int)(p % 2048)] = b; p++; }
        }
    }
}

__global__ __launch_bounds__(256) void memupd_k(const float* __restrict__ memory,
        const float* __restrict__ momentum, const float* __restrict__ scores,
        const float* __restrict__ hbuf, const float* __restrict__ sur, const int* __restrict__ inv,
        float* __restrict__ mem_o, float* __restrict__ mom_o, float* __restrict__ sc_o)
{
    int m = blockIdx.x, t = threadIdx.x;
    int b = inv[m];
    long long o = (long long)m * 256 + t;
    float xm = memory[o], mo = momentum[o];
    if (b >= 0) {
        float diff = hbuf[b * 256 + t] - xm;
        float nmom = 0.9f * mo + 0.1f * diff;
        mem_o[o] = xm + 0.1f * nmom;
        mom_o[o] = nmom;
        if (t == 0) sc_o[m] = sur[b];
    } else {
        mem_o[o] = xm;
        mom_o[o] = mo;
        if (t == 0) sc_o[m] = scores[m];
    }
}

extern "C" void kernel_launch(void* const* d_in, const int* in_sizes, int n_in,
                              void* d_out, int out_size, void* d_ws, size_t ws_size,
                              hipStream_t stream)
{
    const float* src      = (const float*)d_in[0];
    const float* memory   = (const float*)d_in[1];
    const float* momentum = (const float*)d_in[2];
    const float* scores   = (const float*)d_in[3];
    const float* ipw      = (const float*)d_in[4];
    const float* ipb      = (const float*)d_in[5];
    const float* out_w    = (const float*)d_in[6];
    const float* out_b    = (const float*)d_in[7];
    const float* w1       = (const float*)d_in[8];
    const float* b1       = (const float*)d_in[9];
    const float* w2       = (const float*)d_in[10];
    const float* b2       = (const float*)d_in[11];
    const float* g1       = (const float*)d_in[12];
    const float* be1      = (const float*)d_in[13];
    const float* g2       = (const float*)d_in[14];
    const float* be2      = (const float*)d_in[15];
    const int*   ptr      = (const int*)d_in[16];

    float* o = (float*)d_out;
    float* out_main = o;
    float* mem_o = o + 65536;
    float* mom_o = mem_o + 524288;
    float* sc_o  = mom_o + 524288;

    float* ws = (float*)d_ws;
    float* qkv       = ws;                       // 196608
    float* ktvt      = qkv + 196608;             // 1048576  (K^T | V^T, [512][2048])
    float* simdot_p  = ktvt + 1048576;           // 2 * 524288
    float* nx        = simdot_p + 1048576;       // 256
    float* nm        = nx + 256;                 // 2048
    float* nm2       = nm + 2048;                // 2048
    float* sur       = nm2 + 2048;               // 256
    float* ctx       = sur + 256;                // 65536
    float* hbuf      = ctx + 65536;              // 65536
    float* ff1       = hbuf + 65536;             // 262144
    int*   inv       = (int*)(ff1 + 262144);     // 2048
    float* qkv_part  = (float*)(inv + 2048);     // 4 * 196608
    float* attn_part = qkv_part + 786432;        // 8 * 65536
    float* ff1_part  = attn_part + 524288;       // 4 * 262144
    float* ff2_part  = ff1_part + 1048576;       // 16 * 65536

    row_norms<<<2304, 64, 0, stream>>>(src, memory, nx, nm, nm2);

    // qkv_src [256,768] = src @ ipw^T + ipb  (k-split 4 -> 192 blocks)
    gemm_nt<<<dim3(12, 4, 4), 256, 0, stream>>>(src, 256, 0, ipw, 256, 0,
        qkv_part, 768, 0, 196608, nullptr, 256, 768, 256, 1.f, 0, 4, 0);
    reduce_parts<<<768, 256, 0, stream>>>(qkv_part, 4, 196608, ipb, 768, 0, qkv, 196608);

    // ktvt [512,2048] = (memory @ ipw[256:768]^T + ipb[256:768]) transposed  (256 blocks)
    gemm_nt<<<dim3(8, 32, 1), 256, 0, stream>>>(memory, 256, 0, ipw + 65536, 256, 0,
        ktvt, 2048, 0, 0, ipb + 256, 2048, 512, 256, 1.f, 0, 1, 1);

    // simdot [256,2048] = src @ memory^T  (k-split 2 -> 256 blocks)
    gemm_nt<<<dim3(32, 4, 2), 256, 0, stream>>>(src, 256, 0, memory, 256, 0,
        simdot_p, 2048, 0, 524288, nullptr, 256, 2048, 256, 1.f, 0, 2, 0);
    surprise_k<<<256, 256, 0, stream>>>(simdot_p, 2, 524288, nx, nm, nm2, sur);

    // fused attention -> ctx  (512 blocks, 4 waves each, barrier-free)
    attn_k<<<dim3(64, 8), 256, 0, stream>>>(qkv, ktvt, ctx);

    // attn_out partials = ctx @ out_w^T  (k-split 8 -> 128 blocks)
    gemm_nt<<<dim3(4, 4, 8), 256, 0, stream>>>(ctx, 256, 0, out_w, 256, 0,
        attn_part, 256, 0, 65536, nullptr, 256, 256, 256, 1.f, 0, 8, 0);
    // h = LN(src + attn_out + out_b)
    ln_red_k<<<256, 256, 0, stream>>>(attn_part, 8, out_b, src, g1, be1, hbuf);

    accept_k<<<1, 256, 0, stream>>>(sur, ptr, inv);
    memupd_k<<<2048, 256, 0, stream>>>(memory, momentum, scores, hbuf, sur, inv, mem_o, mom_o, sc_o);

    // ff1 = relu(h @ w1^T + b1)  (k-split 4 -> 256 blocks)
    gemm_nt<<<dim3(16, 4, 4), 256, 0, stream>>>(hbuf, 256, 0, w1, 256, 0,
        ff1_part, 1024, 0, 262144, nullptr, 256, 1024, 256, 1.f, 0, 4, 0);
    reduce_parts<<<1024, 256, 0, stream>>>(ff1_part, 4, 262144, b1, 1024, 1, ff1, 262144);

    // ff2 partials = ff1 @ w2^T  (k-split 16 -> 256 blocks)
    gemm_nt<<<dim3(4, 4, 16), 256, 0, stream>>>(ff1, 1024, 0, w2, 1024, 0,
        ff2_part, 256, 0, 65536, nullptr, 256, 256, 1024, 1.f, 0, 16, 0);
    // out = LN(h + ff2 + b2)
    ln_red_k<<<256, 256, 0, stream>>>(ff2_part, 16, b2, hbuf, g2, be2, out_main);
}

// Round 5
// 232.666 us; speedup vs baseline: 1.3186x; 1.2748x over previous
//
#include <hip/hip_runtime.h>
#include <math.h>

// B=256, D=256, H=8, HD=32, FF=1024, M=2048
#define SCALE_F 0.17677669529663687f

typedef __attribute__((ext_vector_type(8))) short short8;
typedef __attribute__((ext_vector_type(4))) float f32x4;

__device__ inline short tobf(float x) {
    unsigned u = __float_as_uint(x);
    unsigned r = (u + 0x7FFFu + ((u >> 16) & 1u)) >> 16;
    return (short)r;
}
__device__ inline float frombf(short s) {
    return __uint_as_float(((unsigned)(unsigned short)s) << 16);
}

// ---------- conversions + split-bf16 packs ----------
// srcsplit [256][768] = [hi|hi|lo]; memsplit [2048][768] = [hi|lo|hi]
// (split trick: x*y ~= xh*yh + xh*yl + xl*yh, error ~2^-17 rel -> f32-grade sims)
__global__ __launch_bounds__(256) void cvt_k(
    const float* __restrict__ src, const float* __restrict__ memory,
    const float* __restrict__ ipw, const float* __restrict__ out_w,
    const float* __restrict__ w1, const float* __restrict__ w2,
    short* __restrict__ srcsplit, short* __restrict__ memsplit,
    short* __restrict__ ipw_bf, short* __restrict__ outw_bf,
    short* __restrict__ w1_bf, short* __restrict__ w2_bf)
{
    int i = blockIdx.x * 256 + threadIdx.x;
    if (i < 65536) {
        float x = src[i];
        short hi = tobf(x); short lo = tobf(x - frombf(hi));
        int r = i >> 8, c = i & 255; long long b = (long long)r * 768;
        srcsplit[b + c] = hi; srcsplit[b + 256 + c] = hi; srcsplit[b + 512 + c] = lo;
    } else if (i < 589824) {
        int j = i - 65536;
        float x = memory[j];
        short hi = tobf(x); short lo = tobf(x - frombf(hi));
        int r = j >> 8, c = j & 255; long long b = (long long)r * 768;
        memsplit[b + c] = hi; memsplit[b + 256 + c] = lo; memsplit[b + 512 + c] = hi;
    } else if (i < 786432) {
        int j = i - 589824; ipw_bf[j] = tobf(ipw[j]);
    } else if (i < 851968) {
        int j = i - 786432; outw_bf[j] = tobf(out_w[j]);
    } else if (i < 1114112) {
        int j = i - 851968; w1_bf[j] = tobf(w1[j]);
    } else {
        int j = i - 1114112; w2_bf[j] = tobf(w2[j]);
    }
}

// ---------- bf16 MFMA GEMM: C[M,N] = alpha*A[M,K]@B[N,K]^T (+bias, relu) ----------
// 64x64 tile, 4 waves (wave w -> rows w*16..w*16+15), K-step 32.
// Fragment layout (16x16x32 bf16): A/B lane l holds 8 contiguous k at row/col (l&15),
// k-base (l>>4)*8; C/D col=lane&15, row=(lane>>4)*4+reg  [guide m89-verified].
// Cf (f32) or Cb (bf16) output; batch-z via sAz/sBz/sCz; k-split via kSplit/sCk; transC.
__global__ __launch_bounds__(256) void gemm_bf(
    const short* __restrict__ A, int lda, long long sAz,
    const short* __restrict__ B, int ldb, long long sBz,
    float* __restrict__ Cf, short* __restrict__ Cb, int ldc,
    long long sCz, long long sCk,
    const float* __restrict__ bias,
    int M, int N, int K, float alpha, int relu, int kSplit, int transC)
{
    __shared__ short Al[64][40];   // +8 pad -> <=2-way LDS conflicts (free)
    __shared__ short Bl[64][40];
    int z = blockIdx.z, zb = z / kSplit, ks = z - zb * kSplit;
    A += (long long)zb * sAz;
    B += (long long)zb * sBz;
    long long coff = (long long)zb * sCz + (long long)ks * sCk;
    int Klen = K / kSplit, kbeg = ks * Klen;
    int t = threadIdx.x;
    int w = t >> 6, l = t & 63;
    int r0 = blockIdx.y * 64, c0 = blockIdx.x * 64;
    int srow = t >> 2, scol = (t & 3) * 8;
    f32x4 acc[4] = {{0.f,0.f,0.f,0.f},{0.f,0.f,0.f,0.f},{0.f,0.f,0.f,0.f},{0.f,0.f,0.f,0.f}};
    for (int kk = 0; kk < Klen; kk += 32) {
        int k0 = kbeg + kk;
        short8 va = {0,0,0,0,0,0,0,0};
        if (r0 + srow < M) va = *(const short8*)(A + (long long)(r0 + srow) * lda + k0 + scol);
        *(short8*)&Al[srow][scol] = va;
        short8 vb = {0,0,0,0,0,0,0,0};
        if (c0 + srow < N) vb = *(const short8*)(B + (long long)(c0 + srow) * ldb + k0 + scol);
        *(short8*)&Bl[srow][scol] = vb;
        __syncthreads();
        short8 af = *(const short8*)&Al[w * 16 + (l & 15)][(l >> 4) * 8];
        #pragma unroll
        for (int j = 0; j < 4; j++) {
            short8 bf = *(const short8*)&Bl[j * 16 + (l & 15)][(l >> 4) * 8];
            acc[j] = __builtin_amdgcn_mfma_f32_16x16x32_bf16(af, bf, acc[j], 0, 0, 0);
        }
        __syncthreads();
    }
    int lc = l & 15, lr = (l >> 4) * 4;
    #pragma unroll
    for (int j = 0; j < 4; j++) {
        int col = c0 + j * 16 + lc;
        if (col >= N) continue;
        float bv = bias ? bias[col] : 0.f;
        #pragma unroll
        for (int r = 0; r < 4; r++) {
            int row = r0 + w * 16 + lr + r;
            if (row >= M) continue;
            float v = acc[j][r] * alpha + bv;
            if (relu) v = fmaxf(v, 0.f);
            long long idx = coff + (transC ? (long long)col * ldc + row
                                           : (long long)row * ldc + col);
            if (Cf) Cf[idx] = v;
            else    Cb[idx] = tobf(v);
        }
    }
}

// ---------- per-row L2 norms ----------
__global__ void row_norms(const float* __restrict__ src, const float* __restrict__ mem,
                          float* __restrict__ nx, float* __restrict__ nm, float* __restrict__ nm2)
{
    int r = blockIdx.x;
    int lane = threadIdx.x;          // 64 lanes
    const float* row = (r < 256) ? (src + (long long)r * 256) : (mem + (long long)(r - 256) * 256);
    float4 v = *(const float4*)(row + lane * 4);
    float ss = v.x * v.x + v.y * v.y + v.z * v.z + v.w * v.w;
    for (int off = 32; off; off >>= 1) ss += __shfl_down(ss, off, 64);
    if (lane == 0) {
        if (r < 256) nx[r] = fmaxf(sqrtf(ss), 1e-8f);
        else { nm[r - 256] = fmaxf(sqrtf(ss), 1e-8f); nm2[r - 256] = ss; }
    }
}

// ---------- surprise ----------
__global__ __launch_bounds__(256) void surprise_k(const float* __restrict__ simdot,
        const float* __restrict__ nx, const float* __restrict__ nm, const float* __restrict__ nm2,
        float* __restrict__ sur)
{
    __shared__ float red[256];
    int b = blockIdx.x, t = threadIdx.x;
    float tot = 0.f;
    for (int m = t; m < 2048; m += 256) tot += nm2[m];
    red[t] = tot; __syncthreads();
    for (int s = 128; s; s >>= 1) { if (t < s) red[t] += red[t + s]; __syncthreads(); }
    float total = red[0];
    __syncthreads();
    float invx = 1.f / nx[b];
    float mx = -1e30f;
    for (int m = t; m < 2048; m += 256) {
        float s = simdot[(long long)b * 2048 + m] * invx / nm[m];
        mx = fmaxf(mx, s);
    }
    red[t] = mx; __syncthreads();
    for (int s = 128; s; s >>= 1) { if (t < s) red[t] = fmaxf(red[t], red[t + s]); __syncthreads(); }
    if (t == 0) sur[b] = (total == 0.f) ? 1.f : 1.f - red[0];
}

// ---------- in-place bf16 softmax over [M logits | self] ----------
// P row rr = h*256+b holds bf16 logits (already *SCALE); rewritten as normalized probs.
__global__ __launch_bounds__(256) void softmax_bf_k(short* __restrict__ P,
        const short* __restrict__ qkv_bf, float* __restrict__ p_self)
{
    int rr = blockIdx.x;
    int h = rr >> 8, b = rr & 255;
    int t = threadIdx.x;
    __shared__ float red[256];
    __shared__ float s_sl;
    if (t < 32)
        red[t] = frombf(qkv_bf[b * 768 + h * 32 + t]) * frombf(qkv_bf[b * 768 + 256 + h * 32 + t]);
    __syncthreads();
    if (t == 0) { float s = 0.f; for (int i = 0; i < 32; i++) s += red[i]; s_sl = s * SCALE_F; }
    __syncthreads();
    float sl = s_sl;
    __syncthreads();
    short* row = P + (long long)rr * 2048;
    short8 v = *(const short8*)(row + t * 8);
    float e[8]; float mx = sl;
    #pragma unroll
    for (int j = 0; j < 8; j++) { e[j] = frombf(v[j]); mx = fmaxf(mx, e[j]); }
    red[t] = mx; __syncthreads();
    for (int s = 128; s; s >>= 1) { if (t < s) red[t] = fmaxf(red[t], red[t + s]); __syncthreads(); }
    mx = red[0]; __syncthreads();
    float sum = 0.f;
    #pragma unroll
    for (int j = 0; j < 8; j++) { e[j] = __expf(e[j] - mx); sum += e[j]; }
    red[t] = sum; __syncthreads();
    for (int s = 128; s; s >>= 1) { if (t < s) red[t] += red[t + s]; __syncthreads(); }
    float es = __expf(sl - mx);
    float inv = 1.f / (red[0] + es);
    short8 o;
    #pragma unroll
    for (int j = 0; j < 8; j++) o[j] = tobf(e[j] * inv);
    *(short8*)(row + t * 8) = o;
    if (t == 0) p_self[rr] = es * inv;
}

// ---------- ctx epilogue: sum PV partials + self term, emit bf16 ctx ----------
__global__ __launch_bounds__(256) void ctxepi_k(const float* __restrict__ pvpart,
        const float* __restrict__ p_self, const short* __restrict__ qkv_bf,
        short* __restrict__ ctx_bf)
{
    int i = blockIdx.x * 256 + threadIdx.x;      // b*256 + h*32+d
    int b = i >> 8, hd = i & 255;
    int h = hd >> 5, d = hd & 31;
    float s = 0.f;
    #pragma unroll
    for (int p = 0; p < 4; p++) s += pvpart[p * 65536 + h * 8192 + b * 32 + d];
    s += p_self[h * 256 + b] * frombf(qkv_bf[b * 768 + 512 + hd]);
    ctx_bf[b * 256 + hd] = tobf(s);
}

// ---------- fused k-split reduce + bias + residual + LayerNorm (+bf16 copy) ----------
__global__ __launch_bounds__(256) void ln_red_k(const float* __restrict__ parts, int np,
        const float* __restrict__ bias, const float* __restrict__ resid,
        const float* __restrict__ g, const float* __restrict__ be,
        float* __restrict__ O, short* __restrict__ Ob)
{
    int r = blockIdx.x, t = threadIdx.x;
    __shared__ float red[256];
    float x = bias[t] + resid[r * 256 + t];
    for (int p = 0; p < np; p++) x += parts[(long long)p * 65536 + r * 256 + t];
    red[t] = x; __syncthreads();
    for (int s = 128; s; s >>= 1) { if (t < s) red[t] += red[t + s]; __syncthreads(); }
    float mean = red[0] * (1.f / 256.f); __syncthreads();
    float c = x - mean;
    red[t] = c * c; __syncthreads();
    for (int s = 128; s; s >>= 1) { if (t < s) red[t] += red[t + s]; __syncthreads(); }
    float rstd = rsqrtf(red[0] * (1.f / 256.f) + 1e-5f);
    float y = c * rstd * g[t] + be[t];
    O[r * 256 + t] = y;
    if (Ob) Ob[r * 256 + t] = tobf(y);
}

// ---------- sequential accept scan ----------
__global__ __launch_bounds__(256) void accept_k(const float* __restrict__ sur,
        const int* __restrict__ ptr, int* __restrict__ inv)
{
    int t = threadIdx.x;
    __shared__ float s_s[256];
    s_s[t] = sur[t];
    for (int m = t; m < 2048; m += 256) inv[m] = -1;
    __syncthreads();
    if (t == 0) {
        long long p = ptr[0];
        for (int b = 0; b < 256; ++b) {
            bool cond = (s_s[b] > 0.5f) || (p < 2048);
            if (cond) { inv[(int)(p % 2048)] = b; p++; }
        }
    }
}

__global__ __launch_bounds__(256) void memupd_k(const float* __restrict__ memory,
        const float* __restrict__ momentum, const float* __restrict__ scores,
        const float* __restrict__ hbuf, const float* __restrict__ sur, const int* __restrict__ inv,
        float* __restrict__ mem_o, float* __restrict__ mom_o, float* __restrict__ sc_o)
{
    int m = blockIdx.x, t = threadIdx.x;
    int b = inv[m];
    long long o = (long long)m * 256 + t;
    float xm = memory[o], mo = momentum[o];
    if (b >= 0) {
        float diff = hbuf[b * 256 + t] - xm;
        float nmom = 0.9f * mo + 0.1f * diff;
        mem_o[o] = xm + 0.1f * nmom;
        mom_o[o] = nmom;
        if (t == 0) sc_o[m] = sur[b];
    } else {
        mem_o[o] = xm;
        mom_o[o] = mo;
        if (t == 0) sc_o[m] = scores[m];
    }
}

extern "C" void kernel_launch(void* const* d_in, const int* in_sizes, int n_in,
                              void* d_out, int out_size, void* d_ws, size_t ws_size,
                              hipStream_t stream)
{
    const float* src      = (const float*)d_in[0];
    const float* memory   = (const float*)d_in[1];
    const float* momentum = (const float*)d_in[2];
    const float* scores   = (const float*)d_in[3];
    const float* ipw      = (const float*)d_in[4];
    const float* ipb      = (const float*)d_in[5];
    const float* out_w    = (const float*)d_in[6];
    const float* out_b    = (const float*)d_in[7];
    const float* w1       = (const float*)d_in[8];
    const float* b1       = (const float*)d_in[9];
    const float* w2       = (const float*)d_in[10];
    const float* b2       = (const float*)d_in[11];
    const float* g1       = (const float*)d_in[12];
    const float* be1      = (const float*)d_in[13];
    const float* g2       = (const float*)d_in[14];
    const float* be2      = (const float*)d_in[15];
    const int*   ptr      = (const int*)d_in[16];

    float* o = (float*)d_out;
    float* out_main = o;
    float* mem_o = o + 65536;
    float* mom_o = mem_o + 524288;
    float* sc_o  = mom_o + 524288;

    char* wp = (char*)d_ws;
    auto alloc = [&](size_t n) { void* p = (void*)wp; wp += (n + 255) & ~(size_t)255; return p; };
    short* srcsplit = (short*)alloc(393216);     // [256][768] bf16 (hi|hi|lo); cols 0..255 = plain src_bf
    short* memsplit = (short*)alloc(3145728);    // [2048][768] bf16 (hi|lo|hi); cols 512..767 = plain mem_bf
    short* ipw_bf   = (short*)alloc(393216);     // [768][256]
    short* outw_bf  = (short*)alloc(131072);     // [256][256]
    short* w1_bf    = (short*)alloc(524288);     // [1024][256]
    short* w2_bf    = (short*)alloc(524288);     // [256][1024]
    short* qkv_bf   = (short*)alloc(393216);     // [256][768]
    short* k_bf     = (short*)alloc(1048576);    // [2048][256]
    short* vt_bf    = (short*)alloc(1048576);    // [256][2048] (V^T, row h*32+d)
    short* probs_bf = (short*)alloc(8388608);    // [8][256][2048] logits -> probs (in-place softmax)
    short* ctx_bf   = (short*)alloc(131072);     // [256][256]
    short* hbuf_bf  = (short*)alloc(131072);     // [256][256]
    short* ff1_bf   = (short*)alloc(524288);     // [256][1024]
    float* p_self   = (float*)alloc(8192);       // [8*256]
    float* simdot   = (float*)alloc(2097152);    // [256][2048]
    float* pvpart   = (float*)alloc(1048576);    // [4][8][256][32]
    float* attn_part= (float*)alloc(1048576);    // [4][256][256]
    float* ff2_part = (float*)alloc(1048576);    // [4][256][256]
    float* hbuf     = (float*)alloc(262144);     // [256][256] f32
    float* nx       = (float*)alloc(1024);
    float* nm       = (float*)alloc(8192);
    float* nm2      = (float*)alloc(8192);
    float* sur      = (float*)alloc(1024);
    int*   inv      = (int*)alloc(8192);

    cvt_k<<<5376, 256, 0, stream>>>(src, memory, ipw, out_w, w1, w2,
        srcsplit, memsplit, ipw_bf, outw_bf, w1_bf, w2_bf);
    row_norms<<<2304, 64, 0, stream>>>(src, memory, nx, nm, nm2);

    // qkv_bf [256,768] = src @ ipw^T + ipb   (A = srcsplit hi-block, lda 768)
    gemm_bf<<<dim3(12, 4, 1), 256, 0, stream>>>(srcsplit, 768, 0, ipw_bf, 256, 0,
        nullptr, qkv_bf, 768, 0, 0, ipb, 256, 768, 256, 1.f, 0, 1, 0);

    // k_bf [2048,256] = memory @ Wk^T + bk   (A = memsplit hi-block at +512, lda 768)
    gemm_bf<<<dim3(4, 32, 1), 256, 0, stream>>>(memsplit + 512, 768, 0, ipw_bf + 65536, 256, 0,
        nullptr, k_bf, 256, 0, 0, ipb + 256, 2048, 256, 256, 1.f, 0, 1, 0);

    // vt_bf [256,2048] = (memory @ Wv^T + bv)^T  via transC
    gemm_bf<<<dim3(4, 32, 1), 256, 0, stream>>>(memsplit + 512, 768, 0, ipw_bf + 131072, 256, 0,
        nullptr, vt_bf, 2048, 0, 0, ipb + 512, 2048, 256, 256, 1.f, 0, 1, 1);

    // simdot [256,2048] = src @ memory^T via split-bf16 (K=768 packed 3-term)
    gemm_bf<<<dim3(32, 4, 1), 256, 0, stream>>>(srcsplit, 768, 0, memsplit, 768, 0,
        simdot, nullptr, 2048, 0, 0, nullptr, 256, 2048, 768, 1.f, 0, 1, 0);
    surprise_k<<<256, 256, 0, stream>>>(simdot, nx, nm, nm2, sur);

    // logits: per head z=8, [256,2048] = q_h @ k_h^T * SCALE -> bf16 in probs_bf
    gemm_bf<<<dim3(32, 4, 8), 256, 0, stream>>>(qkv_bf, 768, 32, k_bf, 256, 32,
        nullptr, probs_bf, 2048, 524288, 0, nullptr, 256, 2048, 32, SCALE_F, 0, 1, 0);
    softmax_bf_k<<<2048, 256, 0, stream>>>(probs_bf, qkv_bf, p_self);

    // PV: per head, [256,32] = P_h @ V_h  (B = V^T rows), k-split 4 -> 128 blocks
    gemm_bf<<<dim3(1, 4, 32), 256, 0, stream>>>(probs_bf, 2048, 524288, vt_bf, 2048, 65536,
        pvpart, nullptr, 32, 8192, 65536, nullptr, 256, 32, 2048, 1.f, 0, 4, 0);
    ctxepi_k<<<256, 256, 0, stream>>>(pvpart, p_self, qkv_bf, ctx_bf);

    // attn_out partials = ctx @ out_w^T  (k-split 4)
    gemm_bf<<<dim3(4, 4, 4), 256, 0, stream>>>(ctx_bf, 256, 0, outw_bf, 256, 0,
        attn_part, nullptr, 256, 0, 65536, nullptr, 256, 256, 256, 1.f, 0, 4, 0);
    // h = LN(src + attn_out + out_b)  (f32 + bf16 copies)
    ln_red_k<<<256, 256, 0, stream>>>(attn_part, 4, out_b, src, g1, be1, hbuf, hbuf_bf);

    accept_k<<<1, 256, 0, stream>>>(sur, ptr, inv);
    memupd_k<<<2048, 256, 0, stream>>>(memory, momentum, scores, hbuf, sur, inv, mem_o, mom_o, sc_o);

    // ff1_bf = relu(h @ w1^T + b1)
    gemm_bf<<<dim3(16, 4, 1), 256, 0, stream>>>(hbuf_bf, 256, 0, w1_bf, 256, 0,
        nullptr, ff1_bf, 1024, 0, 0, b1, 256, 1024, 256, 1.f, 1, 1, 0);
    // ff2 partials = ff1 @ w2^T  (k-split 4)
    gemm_bf<<<dim3(4, 4, 4), 256, 0, stream>>>(ff1_bf, 1024, 0, w2_bf, 1024, 0,
        ff2_part, nullptr, 256, 0, 65536, nullptr, 256, 256, 1024, 1.f, 0, 4, 0);
    // out = LN(h + ff2 + b2)
    ln_red_k<<<256, 256, 0, stream>>>(ff2_part, 4, b2, hbuf, g2, be2, out_main, nullptr);
}

// Round 6
// 190.336 us; speedup vs baseline: 1.6118x; 1.2224x over previous
//
#include <hip/hip_runtime.h>
#include <math.h>

// B=256, D=256, H=8, HD=32, FF=1024, M=2048
#define SCALE_F 0.17677669529663687f

typedef __attribute__((ext_vector_type(8))) short short8;
typedef __attribute__((ext_vector_type(4))) float f32x4;

__device__ inline short tobf(float x) {
    unsigned u = __float_as_uint(x);
    unsigned r = (u + 0x7FFFu + ((u >> 16) & 1u)) >> 16;
    return (short)r;
}
__device__ inline float frombf(short s) {
    return __uint_as_float(((unsigned)(unsigned short)s) << 16);
}

// ---------- conversions + split packs + row norms (fused) ----------
// blocks 0..255: src rows (also nx); 256..2303: memory rows (also nm, nm2); rest: weights
__global__ __launch_bounds__(256) void cvt_k(
    const float* __restrict__ src, const float* __restrict__ memory,
    const float* __restrict__ ipw, const float* __restrict__ out_w,
    const float* __restrict__ w1, const float* __restrict__ w2,
    short* __restrict__ srcsplit, short* __restrict__ memsplit,
    short* __restrict__ ipw_bf, short* __restrict__ outw_bf,
    short* __restrict__ w1_bf, short* __restrict__ w2_bf,
    float* __restrict__ nx, float* __restrict__ nm, float* __restrict__ nm2)
{
    int bid = blockIdx.x, t = threadIdx.x;
    __shared__ float red[256];
    if (bid < 2304) {
        bool issrc = bid < 256;
        int r = issrc ? bid : bid - 256;
        float x = issrc ? src[r * 256 + t] : memory[r * 256 + t];
        short hi = tobf(x); short lo = tobf(x - frombf(hi));
        long long b = (long long)r * 768;
        if (issrc) { srcsplit[b + t] = hi; srcsplit[b + 256 + t] = hi; srcsplit[b + 512 + t] = lo; }
        else       { memsplit[b + t] = hi; memsplit[b + 256 + t] = lo; memsplit[b + 512 + t] = hi; }
        red[t] = x * x; __syncthreads();
        for (int s = 128; s; s >>= 1) { if (t < s) red[t] += red[t + s]; __syncthreads(); }
        if (t == 0) {
            if (issrc) nx[r] = fmaxf(sqrtf(red[0]), 1e-8f);
            else { nm[r] = fmaxf(sqrtf(red[0]), 1e-8f); nm2[r] = red[0]; }
        }
    } else {
        int i = bid * 256 + t;
        int j = i - 589824;
        if (i < 786432)       ipw_bf[j] = tobf(ipw[j]);
        else if (i < 851968)  outw_bf[j - 196608] = tobf(out_w[j - 196608]);
        else if (i < 1114112) w1_bf[j - 262144] = tobf(w1[j - 262144]);
        else                  w2_bf[j - 524288] = tobf(w2[j - 524288]);
    }
}

// ---------- shared tile GEMM body: C[M,N] = alpha*A[M,K]@B[N,K]^T ----------
__device__ __forceinline__ void gemm_tile(
    const short* __restrict__ A, int lda, const short* __restrict__ B, int ldb,
    float* __restrict__ Cf, short* __restrict__ Cb, int ldc, long long coff,
    const float* __restrict__ bias, int M, int N, int Klen, int kbeg,
    float alpha, int relu, int transC, int bx, int by)
{
    __shared__ short Al[64][40];
    __shared__ short Bl[64][40];
    int t = threadIdx.x;
    int w = t >> 6, l = t & 63;
    int r0 = by * 64, c0 = bx * 64;
    int srow = t >> 2, scol = (t & 3) * 8;
    f32x4 acc[4] = {{0.f,0.f,0.f,0.f},{0.f,0.f,0.f,0.f},{0.f,0.f,0.f,0.f},{0.f,0.f,0.f,0.f}};
    for (int kk = 0; kk < Klen; kk += 32) {
        int k0 = kbeg + kk;
        short8 va = {0,0,0,0,0,0,0,0};
        if (r0 + srow < M) va = *(const short8*)(A + (long long)(r0 + srow) * lda + k0 + scol);
        *(short8*)&Al[srow][scol] = va;
        short8 vb = {0,0,0,0,0,0,0,0};
        if (c0 + srow < N) vb = *(const short8*)(B + (long long)(c0 + srow) * ldb + k0 + scol);
        *(short8*)&Bl[srow][scol] = vb;
        __syncthreads();
        short8 af = *(const short8*)&Al[w * 16 + (l & 15)][(l >> 4) * 8];
        #pragma unroll
        for (int j = 0; j < 4; j++) {
            short8 bf = *(const short8*)&Bl[j * 16 + (l & 15)][(l >> 4) * 8];
            acc[j] = __builtin_amdgcn_mfma_f32_16x16x32_bf16(af, bf, acc[j], 0, 0, 0);
        }
        __syncthreads();
    }
    int lc = l & 15, lr = (l >> 4) * 4;
    #pragma unroll
    for (int j = 0; j < 4; j++) {
        int col = c0 + j * 16 + lc;
        if (col >= N) continue;
        float bv = bias ? bias[col] : 0.f;
        #pragma unroll
        for (int r = 0; r < 4; r++) {
            int row = r0 + w * 16 + lr + r;
            if (row >= M) continue;
            float v = acc[j][r] * alpha + bv;
            if (relu) v = fmaxf(v, 0.f);
            long long idx = coff + (transC ? (long long)col * ldc + row
                                           : (long long)row * ldc + col);
            if (Cf) Cf[idx] = v;
            else    Cb[idx] = tobf(v);
        }
    }
}

// ---------- grouped projections: simdot | k_bf | vt_bf | qkv in one launch ----------
__global__ __launch_bounds__(256) void gemm4_k(
    const short* __restrict__ srcsplit, const short* __restrict__ memsplit,
    const short* __restrict__ ipw_bf, const float* __restrict__ ipb,
    float* __restrict__ simdot, short* __restrict__ qkv_bf,
    short* __restrict__ k_bf, short* __restrict__ vt_bf)
{
    int bid = blockIdx.x;
    const short *A, *B; const float *bias; float *Cf; short *Cb;
    int lda, ldb, ldc, M, N, K, relu = 0, transC, bx, by; float alpha;
    if (bid < 128) {            // simdot [256,2048] = srcsplit @ memsplit^T (K=768 split trick)
        A = srcsplit; lda = 768; B = memsplit; ldb = 768;
        Cf = simdot; Cb = nullptr; ldc = 2048; bias = nullptr;
        M = 256; N = 2048; K = 768; alpha = 1.f; transC = 0;
        bx = bid & 31; by = bid >> 5;
    } else if (bid < 256) {     // k_bf [2048,256] = mem_hi @ Wk^T + bk
        int r = bid - 128;
        A = memsplit + 512; lda = 768; B = ipw_bf + 65536; ldb = 256;
        Cf = nullptr; Cb = k_bf; ldc = 256; bias = ipb + 256;
        M = 2048; N = 256; K = 256; alpha = 1.f; transC = 0;
        bx = r & 3; by = r >> 2;
    } else if (bid < 384) {     // vt_bf [256,2048] = (mem_hi @ Wv^T + bv)^T
        int r = bid - 256;
        A = memsplit + 512; lda = 768; B = ipw_bf + 131072; ldb = 256;
        Cf = nullptr; Cb = vt_bf; ldc = 2048; bias = ipb + 512;
        M = 2048; N = 256; K = 256; alpha = 1.f; transC = 1;
        bx = r & 3; by = r >> 2;
    } else {                    // qkv_bf [256,768] = src_hi @ ipw^T + ipb
        int r = bid - 384;
        A = srcsplit; lda = 768; B = ipw_bf; ldb = 256;
        Cf = nullptr; Cb = qkv_bf; ldc = 768; bias = ipb;
        M = 256; N = 768; K = 256; alpha = 1.f; transC = 0;
        bx = r % 12; by = r / 12;
    }
    gemm_tile(A, lda, B, ldb, Cf, Cb, ldc, 0, bias, M, N, K, 0, alpha, relu, transC, bx, by);
}

// ---------- remaining k-split GEMMs (attn_out, ff1, ff2) ----------
__global__ __launch_bounds__(256) void gemm_bf(
    const short* __restrict__ A, int lda,
    const short* __restrict__ B, int ldb,
    float* __restrict__ Cf, short* __restrict__ Cb, int ldc, long long sCk,
    const float* __restrict__ bias,
    int M, int N, int K, float alpha, int relu, int kSplit)
{
    int ks = blockIdx.z;
    int Klen = K / kSplit;
    gemm_tile(A, lda, B, ldb, Cf, Cb, ldc, (long long)ks * sCk, bias,
              M, N, Klen, ks * Klen, alpha, relu, 0, blockIdx.x, blockIdx.y);
}

// ---------- surprise ----------
__global__ __launch_bounds__(256) void surprise_k(const float* __restrict__ simdot,
        const float* __restrict__ nx, const float* __restrict__ nm, const float* __restrict__ nm2,
        float* __restrict__ sur)
{
    __shared__ float red[256];
    int b = blockIdx.x, t = threadIdx.x;
    float tot = 0.f;
    for (int m = t; m < 2048; m += 256) tot += nm2[m];
    red[t] = tot; __syncthreads();
    for (int s = 128; s; s >>= 1) { if (t < s) red[t] += red[t + s]; __syncthreads(); }
    float total = red[0];
    __syncthreads();
    float invx = 1.f / nx[b];
    float mx = -1e30f;
    for (int m = t; m < 2048; m += 256) {
        float s = simdot[(long long)b * 2048 + m] * invx / nm[m];
        mx = fmaxf(mx, s);
    }
    red[t] = mx; __syncthreads();
    for (int s = 128; s; s >>= 1) { if (t < s) red[t] = fmaxf(red[t], red[t + s]); __syncthreads(); }
    if (t == 0) sur[b] = (total == 0.f) ? 1.f : 1.f - red[0];
}

// ---------- fused MFMA flash attention (split-m) ----------
// block = (qt 0..3, h 0..7, ms 0..7): 64 q-rows x 256 m-keys, one head.
// QK^T MFMA -> local softmax in regs (shfl over 16-lane groups) -> P to LDS (bf16)
// -> PV MFMA (V^T frags direct from global). Partials (acc, m, l) to ws; comb_k merges.
__global__ __launch_bounds__(256) void flash_k(
    const short* __restrict__ qkv_bf, const short* __restrict__ k_bf,
    const short* __restrict__ vt_bf,
    float* __restrict__ pvpart, float* __restrict__ mpart, float* __restrict__ lpart)
{
    int bid = blockIdx.x;
    int ms = bid & 7, h = (bid >> 3) & 7, qt = bid >> 6;
    int q0 = qt * 64, m0 = ms * 256;
    int S = bid & 63;                       // h*8 + ms
    int t = threadIdx.x, w = t >> 6, l = t & 63;
    __shared__ short Ql[64][40];
    __shared__ short Kl[256][40];
    __shared__ short Pl[64][264];

    { int srow = t >> 2, scol = (t & 3) * 8;
      *(short8*)&Ql[srow][scol] = *(const short8*)(qkv_bf + (q0 + srow) * 768 + h * 32 + scol); }
    #pragma unroll
    for (int s = 0; s < 4; s++) {
        int seg = t + s * 256; int row = seg >> 2, off = (seg & 3) * 8;
        *(short8*)&Kl[row][off] = *(const short8*)(k_bf + (long long)(m0 + row) * 256 + h * 32 + off);
    }
    __syncthreads();

    short8 af = *(const short8*)&Ql[w * 16 + (l & 15)][(l >> 4) * 8];
    f32x4 accL[16];
    #pragma unroll
    for (int j = 0; j < 16; j++) accL[j] = f32x4{0.f, 0.f, 0.f, 0.f};
    #pragma unroll
    for (int j = 0; j < 16; j++) {
        short8 bf = *(const short8*)&Kl[j * 16 + (l & 15)][(l >> 4) * 8];
        accL[j] = __builtin_amdgcn_mfma_f32_16x16x32_bf16(af, bf, accL[j], 0, 0, 0);
    }
    // local softmax: rows r=0..3 (q = w*16 + (l>>4)*4 + r), cols j*16+(l&15)
    int r4 = (l >> 4) * 4;
    float mloc[4], lsum[4];
    #pragma unroll
    for (int r = 0; r < 4; r++) {
        float mx = -1e30f;
        #pragma unroll
        for (int j = 0; j < 16; j++) mx = fmaxf(mx, accL[j][r] * SCALE_F);
        #pragma unroll
        for (int msk = 1; msk < 16; msk <<= 1) mx = fmaxf(mx, __shfl_xor(mx, msk, 64));
        mloc[r] = mx;
    }
    #pragma unroll
    for (int j = 0; j < 16; j++)
        #pragma unroll
        for (int r = 0; r < 4; r++)
            accL[j][r] = __expf(accL[j][r] * SCALE_F - mloc[r]);
    #pragma unroll
    for (int r = 0; r < 4; r++) {
        float ls = 0.f;
        #pragma unroll
        for (int j = 0; j < 16; j++) ls += accL[j][r];
        #pragma unroll
        for (int msk = 1; msk < 16; msk <<= 1) ls += __shfl_xor(ls, msk, 64);
        lsum[r] = ls;
    }
    if ((l & 15) == 0) {
        #pragma unroll
        for (int r = 0; r < 4; r++) {
            int gq = q0 + w * 16 + r4 + r;
            mpart[S * 256 + gq] = mloc[r];
            lpart[S * 256 + gq] = lsum[r];
        }
    }
    #pragma unroll
    for (int j = 0; j < 16; j++)
        #pragma unroll
        for (int r = 0; r < 4; r++)
            Pl[w * 16 + r4 + r][j * 16 + (l & 15)] = tobf(accL[j][r]);
    __syncthreads();
    // PV: out[q][d] = P[q][m] @ V[m][d]; B-frags straight from vt_bf rows
    f32x4 accP[2] = {{0.f,0.f,0.f,0.f},{0.f,0.f,0.f,0.f}};
    #pragma unroll
    for (int ks = 0; ks < 8; ks++) {
        short8 pa = *(const short8*)&Pl[w * 16 + (l & 15)][ks * 32 + (l >> 4) * 8];
        #pragma unroll
        for (int df = 0; df < 2; df++) {
            short8 vb = *(const short8*)(vt_bf + (long long)(h * 32 + df * 16 + (l & 15)) * 2048
                                         + m0 + ks * 32 + (l >> 4) * 8);
            accP[df] = __builtin_amdgcn_mfma_f32_16x16x32_bf16(pa, vb, accP[df], 0, 0, 0);
        }
    }
    #pragma unroll
    for (int df = 0; df < 2; df++)
        #pragma unroll
        for (int r = 0; r < 4; r++) {
            int gq = q0 + w * 16 + r4 + r;
            pvpart[((long long)S * 256 + gq) * 32 + df * 16 + (l & 15)] = accP[df][r];
        }
}

// ---------- combine split-m partials + self term -> ctx_bf ----------
__global__ __launch_bounds__(256) void comb_k(const float* __restrict__ pvpart,
        const float* __restrict__ mpart, const float* __restrict__ lpart,
        const short* __restrict__ qkv_bf, short* __restrict__ ctx_bf)
{
    int b = blockIdx.x, t = threadIdx.x;
    int h = t >> 5, d = t & 31;
    float qv = frombf(qkv_bf[b * 768 + h * 32 + d]);
    float kv = frombf(qkv_bf[b * 768 + 256 + h * 32 + d]);
    float sl = qv * kv;
    #pragma unroll
    for (int msk = 1; msk < 32; msk <<= 1) sl += __shfl_xor(sl, msk, 64);
    sl *= SCALE_F;
    float vs = frombf(qkv_bf[b * 768 + 512 + h * 32 + d]);
    float ms_[8];
    float Mf = sl;
    #pragma unroll
    for (int s = 0; s < 8; s++) { ms_[s] = mpart[(h * 8 + s) * 256 + b]; Mf = fmaxf(Mf, ms_[s]); }
    float es = __expf(sl - Mf);
    float lsum = es, a = es * vs;
    #pragma unroll
    for (int s = 0; s < 8; s++) {
        float wgt = __expf(ms_[s] - Mf);
        lsum += wgt * lpart[(h * 8 + s) * 256 + b];
        a += wgt * pvpart[((long long)(h * 8 + s) * 256 + b) * 32 + d];
    }
    ctx_bf[b * 256 + t] = tobf(a / lsum);
}

// ---------- fused k-split reduce + bias + residual + LayerNorm (+bf16 copy) ----------
__global__ __launch_bounds__(256) void ln_red_k(const float* __restrict__ parts, int np,
        const float* __restrict__ bias, const float* __restrict__ resid,
        const float* __restrict__ g, const float* __restrict__ be,
        float* __restrict__ O, short* __restrict__ Ob)
{
    int r = blockIdx.x, t = threadIdx.x;
    __shared__ float red[256];
    float x = bias[t] + resid[r * 256 + t];
    for (int p = 0; p < np; p++) x += parts[(long long)p * 65536 + r * 256 + t];
    red[t] = x; __syncthreads();
    for (int s = 128; s; s >>= 1) { if (t < s) red[t] += red[t + s]; __syncthreads(); }
    float mean = red[0] * (1.f / 256.f); __syncthreads();
    float c = x - mean;
    red[t] = c * c; __syncthreads();
    for (int s = 128; s; s >>= 1) { if (t < s) red[t] += red[t + s]; __syncthreads(); }
    float rstd = rsqrtf(red[0] * (1.f / 256.f) + 1e-5f);
    float y = c * rstd * g[t] + be[t];
    O[r * 256 + t] = y;
    if (Ob) Ob[r * 256 + t] = tobf(y);
}

// ---------- memory update with fused accept scan ----------
__global__ __launch_bounds__(256) void memupd_k(const float* __restrict__ memory,
        const float* __restrict__ momentum, const float* __restrict__ scores,
        const float* __restrict__ hbuf, const float* __restrict__ sur,
        const int* __restrict__ ptr,
        float* __restrict__ mem_o, float* __restrict__ mom_o, float* __restrict__ sc_o)
{
    int m = blockIdx.x, t = threadIdx.x;
    __shared__ float s_s[256];
    __shared__ int s_found;
    __shared__ float s_sv;
    s_s[t] = sur[t];
    __syncthreads();
    if (t == 0) {
        int found = -1; float sv = 0.f;
        long long p = ptr[0];
        for (int b = 0; b < 256; ++b) {
            float sb = s_s[b];
            bool cond = (sb > 0.5f) || (p < 2048);
            if (cond) { if ((int)(p & 2047) == m) { found = b; sv = sb; } p++; }
        }
        s_found = found; s_sv = sv;
    }
    __syncthreads();
    int b = s_found;
    long long o = (long long)m * 256 + t;
    float xm = memory[o], mo = momentum[o];
    if (b >= 0) {
        float diff = hbuf[b * 256 + t] - xm;
        float nmom = 0.9f * mo + 0.1f * diff;
        mem_o[o] = xm + 0.1f * nmom;
        mom_o[o] = nmom;
        if (t == 0) sc_o[m] = s_sv;
    } else {
        mem_o[o] = xm;
        mom_o[o] = mo;
        if (t == 0) sc_o[m] = scores[m];
    }
}

extern "C" void kernel_launch(void* const* d_in, const int* in_sizes, int n_in,
                              void* d_out, int out_size, void* d_ws, size_t ws_size,
                              hipStream_t stream)
{
    const float* src      = (const float*)d_in[0];
    const float* memory   = (const float*)d_in[1];
    const float* momentum = (const float*)d_in[2];
    const float* scores   = (const float*)d_in[3];
    const float* ipw      = (const float*)d_in[4];
    const float* ipb      = (const float*)d_in[5];
    const float* out_w    = (const float*)d_in[6];
    const float* out_b    = (const float*)d_in[7];
    const float* w1       = (const float*)d_in[8];
    const float* b1       = (const float*)d_in[9];
    const float* w2       = (const float*)d_in[10];
    const float* b2       = (const float*)d_in[11];
    const float* g1       = (const float*)d_in[12];
    const float* be1      = (const float*)d_in[13];
    const float* g2       = (const float*)d_in[14];
    const float* be2      = (const float*)d_in[15];
    const int*   ptr      = (const int*)d_in[16];

    float* o = (float*)d_out;
    float* out_main = o;
    float* mem_o = o + 65536;
    float* mom_o = mem_o + 524288;
    float* sc_o  = mom_o + 524288;

    char* wp = (char*)d_ws;
    auto alloc = [&](size_t n) { void* p = (void*)wp; wp += (n + 255) & ~(size_t)255; return p; };
    short* srcsplit = (short*)alloc(393216);     // [256][768] (hi|hi|lo)
    short* memsplit = (short*)alloc(3145728);    // [2048][768] (hi|lo|hi)
    short* ipw_bf   = (short*)alloc(393216);     // [768][256]
    short* outw_bf  = (short*)alloc(131072);     // [256][256]
    short* w1_bf    = (short*)alloc(524288);     // [1024][256]
    short* w2_bf    = (short*)alloc(524288);     // [256][1024]
    short* qkv_bf   = (short*)alloc(393216);     // [256][768]
    short* k_bf     = (short*)alloc(1048576);    // [2048][256]
    short* vt_bf    = (short*)alloc(1048576);    // [256][2048]
    short* ctx_bf   = (short*)alloc(131072);     // [256][256]
    short* hbuf_bf  = (short*)alloc(131072);     // [256][256]
    short* ff1_bf   = (short*)alloc(524288);     // [256][1024]
    float* simdot   = (float*)alloc(2097152);    // [256][2048]
    float* pvpart   = (float*)alloc(2097152);    // [64 S][256 q][32 d]
    float* mpart    = (float*)alloc(65536);      // [64 S][256 q]
    float* lpart    = (float*)alloc(65536);
    float* attn_part= (float*)alloc(2097152);    // [8][256][256]
    float* ff2_part = (float*)alloc(4194304);    // [16][256][256]
    float* hbuf     = (float*)alloc(262144);     // [256][256] f32
    float* nx       = (float*)alloc(1024);
    float* nm       = (float*)alloc(8192);
    float* nm2      = (float*)alloc(8192);
    float* sur      = (float*)alloc(1024);

    // 1. convert + split packs + row norms
    cvt_k<<<5376, 256, 0, stream>>>(src, memory, ipw, out_w, w1, w2,
        srcsplit, memsplit, ipw_bf, outw_bf, w1_bf, w2_bf, nx, nm, nm2);

    // 2. grouped projections (simdot | k | vt | qkv), 432 blocks
    gemm4_k<<<432, 256, 0, stream>>>(srcsplit, memsplit, ipw_bf, ipb,
        simdot, qkv_bf, k_bf, vt_bf);

    // 3. fused flash attention (split-m), 4. combine
    flash_k<<<256, 256, 0, stream>>>(qkv_bf, k_bf, vt_bf, pvpart, mpart, lpart);
    comb_k<<<256, 256, 0, stream>>>(pvpart, mpart, lpart, qkv_bf, ctx_bf);

    // 5. surprise
    surprise_k<<<256, 256, 0, stream>>>(simdot, nx, nm, nm2, sur);

    // 6. attn_out partials = ctx @ out_w^T (k-split 8 -> 128 blocks)
    gemm_bf<<<dim3(4, 4, 8), 256, 0, stream>>>(ctx_bf, 256, outw_bf, 256,
        attn_part, nullptr, 256, 65536, nullptr, 256, 256, 256, 1.f, 0, 8);
    // 7. h = LN(src + attn_out + out_b)
    ln_red_k<<<256, 256, 0, stream>>>(attn_part, 8, out_b, src, g1, be1, hbuf, hbuf_bf);

    // 8. memory update (accept scan fused)
    memupd_k<<<2048, 256, 0, stream>>>(memory, momentum, scores, hbuf, sur, ptr,
        mem_o, mom_o, sc_o);

    // 9. ff1 = relu(h @ w1^T + b1), 64 blocks
    gemm_bf<<<dim3(16, 4, 1), 256, 0, stream>>>(hbuf_bf, 256, w1_bf, 256,
        nullptr, ff1_bf, 1024, 0, b1, 256, 1024, 256, 1.f, 1, 1);
    // 10. ff2 partials = ff1 @ w2^T (k-split 16 -> 256 blocks)
    gemm_bf<<<dim3(4, 4, 16), 256, 0, stream>>>(ff1_bf, 1024, w2_bf, 1024,
        ff2_part, nullptr, 256, 65536, nullptr, 256, 256, 1024, 1.f, 0, 16);
    // 11. out = LN(h + ff2 + b2)
    ln_red_k<<<256, 256, 0, stream>>>(ff2_part, 16, b2, hbuf, g2, be2, out_main, nullptr);
}